// Round 2
// baseline (692.160 us; speedup 1.0000x reference)
//
#include <hip/hip_runtime.h>
#include <stdint.h>

// Problem constants
#define B_SZ 2
#define T_SEQ 2048
#define DM 2048
#define NH 32
#define NKV 8
#define HD 64
#define QKV_W 3072

typedef unsigned short u16;
typedef __bf16 bf16x8 __attribute__((ext_vector_type(8)));
typedef float floatx4 __attribute__((ext_vector_type(4)));

__device__ __forceinline__ float bf2f(u16 u) {
  union { unsigned u; float f; } v; v.u = ((unsigned)u) << 16; return v.f;
}
__device__ __forceinline__ u16 f2bf(float f) {
  union { float f; unsigned u; } v; v.f = f;
  unsigned r = v.u + 0x7fff + ((v.u >> 16) & 1);   // RNE
  return (u16)(r >> 16);
}

__device__ __forceinline__ void gld_lds16(const void* g, void* l) {
  __builtin_amdgcn_global_load_lds(
      (const __attribute__((address_space(1))) unsigned int*)g,
      (__attribute__((address_space(3))) unsigned int*)l, 16, 0, 0);
}

// ---------------------------------------------------------------------------
// f32 -> bf16 conversion (RNE), vectorized float4 -> ushort4, grid-stride.
// n4 = element count / 4.
// ---------------------------------------------------------------------------
__global__ __launch_bounds__(256) void conv_kernel(
    const float* __restrict__ src, u16* __restrict__ dst, int n4)
{
  int i = blockIdx.x * 256 + threadIdx.x;
  int stride = gridDim.x * 256;
  for (; i < n4; i += stride) {
    float4 v = ((const float4*)src)[i];
    ushort4 o;
    o.x = f2bf(v.x); o.y = f2bf(v.y); o.z = f2bf(v.z); o.w = f2bf(v.w);
    ((ushort4*)dst)[i] = o;
  }
}

// ---------------------------------------------------------------------------
// GEMM1: qkv[4096,3072](bf16) = xb[4096,2048](bf16) @ wqkvb[3072,2048]^T
// m97 structure: 128x128 tile, BK=32, 4 waves each 64x64, global_load_lds w=16
// ---------------------------------------------------------------------------
__global__ __launch_bounds__(256) void gemm_qkv_kernel(
    const u16* __restrict__ A, const u16* __restrict__ Bt,
    u16* __restrict__ C)
{
  __shared__ __align__(16) u16 sA[128 * 32];
  __shared__ __align__(16) u16 sB[128 * 32];

  const int n0 = blockIdx.x * 128;
  const int m0 = blockIdx.y * 128;
  const int K = 2048;

  const int tid  = threadIdx.x;
  const int lane = tid & 63;
  const int w    = tid >> 6;
  const int wm = w >> 1, wn = w & 1;
  const int lm = lane & 15, lq = lane >> 4;

  floatx4 acc[4][4];
  #pragma unroll
  for (int i = 0; i < 4; i++)
    #pragma unroll
    for (int j = 0; j < 4; j++) { floatx4 z = {0.f,0.f,0.f,0.f}; acc[i][j] = z; }

  const int ar = tid >> 2;        // 0..63
  const int ac = (tid & 3) * 8;   // 0,8,16,24
  const u16* Ap0 = A  + (size_t)(m0 + ar) * K + ac;
  const u16* Ap1 = A  + (size_t)(m0 + 64 + ar) * K + ac;
  const u16* Bp0 = Bt + (size_t)(n0 + ar) * K + ac;
  const u16* Bp1 = Bt + (size_t)(n0 + 64 + ar) * K + ac;
  u16* sAd = sA + tid * 8;
  u16* sBd = sB + tid * 8;

  for (int k0 = 0; k0 < K; k0 += 32) {
    gld_lds16(Ap0 + k0, sAd);
    gld_lds16(Ap1 + k0, sAd + 2048);
    gld_lds16(Bp0 + k0, sBd);
    gld_lds16(Bp1 + k0, sBd + 2048);
    __syncthreads();

    bf16x8 af[4], bfr[4];
    #pragma unroll
    for (int mi = 0; mi < 4; mi++)
      af[mi] = *(const bf16x8*)(sA + (wm*64 + mi*16 + lm)*32 + lq*8);
    #pragma unroll
    for (int ni = 0; ni < 4; ni++)
      bfr[ni] = *(const bf16x8*)(sB + (wn*64 + ni*16 + lm)*32 + lq*8);

    #pragma unroll
    for (int mi = 0; mi < 4; mi++)
      #pragma unroll
      for (int ni = 0; ni < 4; ni++)
        acc[mi][ni] = __builtin_amdgcn_mfma_f32_16x16x32_bf16(
            af[mi], bfr[ni], acc[mi][ni], 0, 0, 0);
    __syncthreads();
  }

  #pragma unroll
  for (int mi = 0; mi < 4; mi++)
    #pragma unroll
    for (int ni = 0; ni < 4; ni++)
      #pragma unroll
      for (int r = 0; r < 4; r++) {
        int row = m0 + wm*64 + mi*16 + lq*4 + r;
        int col = n0 + wn*64 + ni*16 + lm;
        C[(size_t)row * QKV_W + col] = f2bf(acc[mi][ni][r]);
      }
}

// ---------------------------------------------------------------------------
// GEMM2: out[4096,2048](f32) = attn[4096,2048](bf16) @ wob[2048,2048]^T(bf16)
// ---------------------------------------------------------------------------
__global__ __launch_bounds__(256) void gemm_out_kernel(
    const u16* __restrict__ A, const u16* __restrict__ Bt,
    float* __restrict__ C)
{
  __shared__ __align__(16) u16 sA[128 * 32];
  __shared__ __align__(16) u16 sB[128 * 32];

  const int n0 = blockIdx.x * 128;
  const int m0 = blockIdx.y * 128;
  const int K = 2048;

  const int tid  = threadIdx.x;
  const int lane = tid & 63;
  const int w    = tid >> 6;
  const int wm = w >> 1, wn = w & 1;
  const int lm = lane & 15, lq = lane >> 4;

  floatx4 acc[4][4];
  #pragma unroll
  for (int i = 0; i < 4; i++)
    #pragma unroll
    for (int j = 0; j < 4; j++) { floatx4 z = {0.f,0.f,0.f,0.f}; acc[i][j] = z; }

  const int ar = tid >> 2;
  const int ac = (tid & 3) * 8;
  const u16* Ap0 = A  + (size_t)(m0 + ar) * K + ac;
  const u16* Ap1 = A  + (size_t)(m0 + 64 + ar) * K + ac;
  const u16* Bp0 = Bt + (size_t)(n0 + ar) * K + ac;
  const u16* Bp1 = Bt + (size_t)(n0 + 64 + ar) * K + ac;
  u16* sAd = sA + tid * 8;
  u16* sBd = sB + tid * 8;

  for (int k0 = 0; k0 < K; k0 += 32) {
    gld_lds16(Ap0 + k0, sAd);
    gld_lds16(Ap1 + k0, sAd + 2048);
    gld_lds16(Bp0 + k0, sBd);
    gld_lds16(Bp1 + k0, sBd + 2048);
    __syncthreads();

    bf16x8 af[4], bfr[4];
    #pragma unroll
    for (int mi = 0; mi < 4; mi++)
      af[mi] = *(const bf16x8*)(sA + (wm*64 + mi*16 + lm)*32 + lq*8);
    #pragma unroll
    for (int ni = 0; ni < 4; ni++)
      bfr[ni] = *(const bf16x8*)(sB + (wn*64 + ni*16 + lm)*32 + lq*8);

    #pragma unroll
    for (int mi = 0; mi < 4; mi++)
      #pragma unroll
      for (int ni = 0; ni < 4; ni++)
        acc[mi][ni] = __builtin_amdgcn_mfma_f32_16x16x32_bf16(
            af[mi], bfr[ni], acc[mi][ni], 0, 0, 0);
    __syncthreads();
  }

  #pragma unroll
  for (int mi = 0; mi < 4; mi++)
    #pragma unroll
    for (int ni = 0; ni < 4; ni++)
      #pragma unroll
      for (int r = 0; r < 4; r++) {
        int row = m0 + wm*64 + mi*16 + lq*4 + r;
        int col = n0 + wn*64 + ni*16 + lm;
        C[(size_t)row * DM + col] = acc[mi][ni][r];
      }
}

// ---------------------------------------------------------------------------
// RoPE: reads qkv bf16, writes q (B,H,T,64) bf16 (scaled by 1/8) and
// k (B,KV,T,64) bf16. cos/sin tables are f32 (T,64); cos[d]==cos[d+32].
// One block per (b,t).
// ---------------------------------------------------------------------------
__global__ __launch_bounds__(256) void rope_kernel(
    const u16* __restrict__ qkv, const float* __restrict__ cosf,
    const float* __restrict__ sinf, u16* __restrict__ qb, u16* __restrict__ kb)
{
  const int bt = blockIdx.x;
  const int b = bt / T_SEQ, t = bt % T_SEQ;
  const int tid = threadIdx.x;
  const u16* row = qkv + (size_t)bt * QKV_W;

  #pragma unroll
  for (int i = 0; i < 4; i++) {
    int idx = i * 256 + tid;          // 0..1023
    int h = idx >> 5, dp = idx & 31;
    float x1 = bf2f(row[h * 64 + dp]);
    float x2 = bf2f(row[h * 64 + dp + 32]);
    float c = cosf[t * 64 + dp];
    float s = sinf[t * 64 + dp];
    float o1 = (x1 * c - x2 * s) * 0.125f;
    float o2 = (x2 * c + x1 * s) * 0.125f;
    size_t base = ((size_t)(b * NH + h) * T_SEQ + t) * HD + dp;
    qb[base]      = f2bf(o1);
    qb[base + 32] = f2bf(o2);
  }
  {
    int idx = tid;                    // 0..255
    int kvh = idx >> 5, dp = idx & 31;
    float x1 = bf2f(row[2048 + kvh * 64 + dp]);
    float x2 = bf2f(row[2048 + kvh * 64 + dp + 32]);
    float c = cosf[t * 64 + dp];
    float s = sinf[t * 64 + dp];
    size_t base = ((size_t)(b * NKV + kvh) * T_SEQ + t) * HD + dp;
    kb[base]      = f2bf(x1 * c - x2 * s);
    kb[base + 32] = f2bf(x2 * c + x1 * s);
  }
}

// ---------------------------------------------------------------------------
// V transpose: qkv bf16 cols [2560,3072) -> vbt (B,KV,64,T) bf16
// One block per (t-tile of 64, kv, b); LDS 64x66 transpose.
// ---------------------------------------------------------------------------
__global__ __launch_bounds__(256) void vtrans_kernel(
    const u16* __restrict__ qkv, u16* __restrict__ vbt)
{
  __shared__ u16 tile[64][66];
  const int t0  = blockIdx.x * 64;
  const int kvh = blockIdx.y;
  const int b   = blockIdx.z;
  const int tid = threadIdx.x;

  #pragma unroll
  for (int i = 0; i < 16; i++) {
    int idx = i * 256 + tid;
    int r = idx >> 6, c = idx & 63;
    tile[r][c] = qkv[(size_t)(b * T_SEQ + t0 + r) * QKV_W + 2560 + kvh * 64 + c];
  }
  __syncthreads();
  #pragma unroll
  for (int i = 0; i < 16; i++) {
    int idx = i * 256 + tid;
    int d = idx >> 6, c = idx & 63;
    vbt[((size_t)(b * NKV + kvh) * HD + d) * T_SEQ + t0 + c] = tile[c][d];
  }
}

// ---------------------------------------------------------------------------
// Flash attention: block = (q-tile of 64, h, b); 4 waves x 16 q-rows.
// qb has 1/sqrt(HD) folded in. S/O in MFMA C-layout (col=lane&15,
// row=(lane>>4)*4+reg). P converted C-layout -> A-layout via padded LDS.
// ---------------------------------------------------------------------------
__global__ __launch_bounds__(256) void attn_kernel(
    const u16* __restrict__ qb, const u16* __restrict__ kb,
    const u16* __restrict__ vbt, u16* __restrict__ attn)
{
  __shared__ __align__(16) u16 sP[4][16][72];   // +8 pad: 2-way banks (free)
  const int tid  = threadIdx.x;
  const int lane = tid & 63;
  const int w    = tid >> 6;
  const int qt = blockIdx.x;
  const int h  = blockIdx.y;
  const int b  = blockIdx.z;
  const int kv = h >> 2;
  const int lm = lane & 15, lq = lane >> 4;

  const u16* qrow = qb + ((size_t)(b * NH + h) * T_SEQ + (qt * 64 + w * 16 + lm)) * HD + lq * 8;
  bf16x8 qf0 = *(const bf16x8*)(qrow);
  bf16x8 qf1 = *(const bf16x8*)(qrow + 32);

  floatx4 o_acc[4];
  #pragma unroll
  for (int i = 0; i < 4; i++) { floatx4 z = {0.f,0.f,0.f,0.f}; o_acc[i] = z; }
  float m_run[4] = {-1e30f, -1e30f, -1e30f, -1e30f};
  float l_run[4] = {0.f, 0.f, 0.f, 0.f};

  const u16* kbase = kb  + (size_t)(b * NKV + kv) * T_SEQ * HD;
  const u16* vbase = vbt + (size_t)(b * NKV + kv) * HD * T_SEQ;

  for (int kt = 0; kt <= qt; kt++) {
    floatx4 s_acc[4];
    #pragma unroll
    for (int i = 0; i < 4; i++) { floatx4 z = {0.f,0.f,0.f,0.f}; s_acc[i] = z; }

    #pragma unroll
    for (int nt = 0; nt < 4; nt++) {
      const u16* krow = kbase + (size_t)(kt * 64 + nt * 16 + lm) * HD + lq * 8;
      bf16x8 kf0 = *(const bf16x8*)(krow);
      bf16x8 kf1 = *(const bf16x8*)(krow + 32);
      s_acc[nt] = __builtin_amdgcn_mfma_f32_16x16x32_bf16(qf0, kf0, s_acc[nt], 0, 0, 0);
      s_acc[nt] = __builtin_amdgcn_mfma_f32_16x16x32_bf16(qf1, kf1, s_acc[nt], 0, 0, 0);
    }

    if (kt == qt) {   // diagonal tile: causal mask
      #pragma unroll
      for (int nt = 0; nt < 4; nt++)
        #pragma unroll
        for (int r = 0; r < 4; r++)
          if (nt * 16 + lm > w * 16 + lq * 4 + r) s_acc[nt][r] = -1e30f;
    }

    float p[4][4];
    float alpha[4];
    #pragma unroll
    for (int r = 0; r < 4; r++) {
      float mx = fmaxf(fmaxf(s_acc[0][r], s_acc[1][r]), fmaxf(s_acc[2][r], s_acc[3][r]));
      mx = fmaxf(mx, __shfl_xor(mx, 1));
      mx = fmaxf(mx, __shfl_xor(mx, 2));
      mx = fmaxf(mx, __shfl_xor(mx, 4));
      mx = fmaxf(mx, __shfl_xor(mx, 8));
      float mnew = fmaxf(m_run[r], mx);
      float al = __expf(m_run[r] - mnew);
      float rs = 0.f;
      #pragma unroll
      for (int nt = 0; nt < 4; nt++) {
        float pv = __expf(s_acc[nt][r] - mnew);
        p[nt][r] = pv; rs += pv;
      }
      rs += __shfl_xor(rs, 1);
      rs += __shfl_xor(rs, 2);
      rs += __shfl_xor(rs, 4);
      rs += __shfl_xor(rs, 8);
      l_run[r] = l_run[r] * al + rs;
      m_run[r] = mnew;
      alpha[r] = al;
    }
    #pragma unroll
    for (int nt = 0; nt < 4; nt++)
      #pragma unroll
      for (int r = 0; r < 4; r++)
        o_acc[nt][r] *= alpha[r];

    // P: C-layout -> LDS (bf16) -> A-operand layout
    #pragma unroll
    for (int nt = 0; nt < 4; nt++)
      #pragma unroll
      for (int r = 0; r < 4; r++)
        sP[w][lq * 4 + r][nt * 16 + lm] = f2bf(p[nt][r]);

    #pragma unroll
    for (int st = 0; st < 2; st++) {
      bf16x8 pf = *(const bf16x8*)(&sP[w][lm][st * 32 + lq * 8]);
      #pragma unroll
      for (int nt2 = 0; nt2 < 4; nt2++) {
        const u16* vrow = vbase + (size_t)(nt2 * 16 + lm) * T_SEQ + kt * 64 + st * 32 + lq * 8;
        bf16x8 vf = *(const bf16x8*)(vrow);
        o_acc[nt2] = __builtin_amdgcn_mfma_f32_16x16x32_bf16(pf, vf, o_acc[nt2], 0, 0, 0);
      }
    }
  }

  #pragma unroll
  for (int nt2 = 0; nt2 < 4; nt2++)
    #pragma unroll
    for (int r = 0; r < 4; r++) {
      float v = o_acc[nt2][r] / l_run[r];
      size_t row = (size_t)b * T_SEQ + qt * 64 + w * 16 + lq * 4 + r;
      attn[row * DM + h * HD + nt2 * 16 + lm] = f2bf(v);
    }
}

// ---------------------------------------------------------------------------
extern "C" void kernel_launch(void* const* d_in, const int* in_sizes, int n_in,
                              void* d_out, int out_size, void* d_ws, size_t ws_size,
                              hipStream_t stream)
{
  const float* x    = (const float*)d_in[0];
  const float* cosf = (const float*)d_in[1];
  const float* sinf = (const float*)d_in[2];
  const float* Wq   = (const float*)d_in[3];
  const float* Wk   = (const float*)d_in[4];
  const float* Wv   = (const float*)d_in[5];
  const float* Wo   = (const float*)d_in[6];
  float* out = (float*)d_out;

  char* ws = (char*)d_ws;
  // layout (bytes):
  u16* qkvb  = (u16*)(ws + 0);          // 4096x3072 bf16 = 25,165,824
  u16* attnb = (u16*)(ws + 0);          // reuse after rope/vtrans: 16,777,216
  u16* qb    = (u16*)(ws + 25165824);   // 16,777,216
  u16* kb    = (u16*)(ws + 41943040);   //  4,194,304
  u16* vbt   = (u16*)(ws + 46137344);   //  4,194,304
  u16* xb    = (u16*)(ws + 50331648);   // 16,777,216 (dead after gemm_qkv)
  u16* wob   = (u16*)(ws + 50331648);   //  8,388,608 (overwrites xb, after gemm_qkv)
  u16* wqkvb = (u16*)(ws + 67108864);   // 12,582,912  -> total ~76 MB

  dim3 blk(256);
  // f32 -> bf16 conversions
  conv_kernel<<<dim3(2048), blk, 0, stream>>>(x,  xb,                 8388608 / 4);
  conv_kernel<<<dim3(1024), blk, 0, stream>>>(Wq, wqkvb,              4194304 / 4);
  conv_kernel<<<dim3(512),  blk, 0, stream>>>(Wk, wqkvb + 2048*2048,  1048576 / 4);
  conv_kernel<<<dim3(512),  blk, 0, stream>>>(Wv, wqkvb + 2560*2048,  1048576 / 4);

  gemm_qkv_kernel<<<dim3(24, 32), blk, 0, stream>>>(xb, wqkvb, qkvb);

  conv_kernel<<<dim3(1024), blk, 0, stream>>>(Wo, wob, 4194304 / 4);

  rope_kernel<<<dim3(B_SZ * T_SEQ), blk, 0, stream>>>(qkvb, cosf, sinf, qb, kb);
  vtrans_kernel<<<dim3(T_SEQ / 64, NKV, B_SZ), blk, 0, stream>>>(qkvb, vbt);
  attn_kernel<<<dim3(T_SEQ / 64, NH, B_SZ), blk, 0, stream>>>(qb, kb, vbt, attnb);
  gemm_out_kernel<<<dim3(16, 32), blk, 0, stream>>>(attnb, wob, out);
}

// Round 3
// 387.321 us; speedup vs baseline: 1.7870x; 1.7870x over previous
//
#include <hip/hip_runtime.h>
#include <stdint.h>

// Problem constants
#define B_SZ 2
#define T_SEQ 2048
#define DM 2048
#define NH 32
#define NKV 8
#define HD 64
#define QKV_W 3072

typedef unsigned short u16;
typedef __bf16 bf16x8 __attribute__((ext_vector_type(8)));
typedef float floatx4 __attribute__((ext_vector_type(4)));

__device__ __forceinline__ float bf2f(u16 u) {
  union { unsigned u; float f; } v; v.u = ((unsigned)u) << 16; return v.f;
}
__device__ __forceinline__ u16 f2bf(float f) {
  union { float f; unsigned u; } v; v.f = f;
  unsigned r = v.u + 0x7fff + ((v.u >> 16) & 1);   // RNE
  return (u16)(r >> 16);
}

__device__ __forceinline__ void gld_lds16(const void* g, void* l) {
  __builtin_amdgcn_global_load_lds(
      (const __attribute__((address_space(1))) unsigned int*)g,
      (__attribute__((address_space(3))) unsigned int*)l, 16, 0, 0);
}

// ---------------------------------------------------------------------------
// f32 -> bf16 conversion (RNE), vectorized float4 -> ushort4, grid-stride.
// ---------------------------------------------------------------------------
__global__ __launch_bounds__(256) void conv_kernel(
    const float* __restrict__ src, u16* __restrict__ dst, int n4)
{
  int i = blockIdx.x * 256 + threadIdx.x;
  int stride = gridDim.x * 256;
  for (; i < n4; i += stride) {
    float4 v = ((const float4*)src)[i];
    ushort4 o;
    o.x = f2bf(v.x); o.y = f2bf(v.y); o.z = f2bf(v.z); o.w = f2bf(v.w);
    ((ushort4*)dst)[i] = o;
  }
}

// ---------------------------------------------------------------------------
// GEMM1: qkv[4096,3072](bf16) = xb[4096,2048](bf16) @ wqkvb[3072,2048]^T
// ---------------------------------------------------------------------------
__global__ __launch_bounds__(256) void gemm_qkv_kernel(
    const u16* __restrict__ A, const u16* __restrict__ Bt,
    u16* __restrict__ C)
{
  __shared__ __align__(16) u16 sA[128 * 32];
  __shared__ __align__(16) u16 sB[128 * 32];

  const int n0 = blockIdx.x * 128;
  const int m0 = blockIdx.y * 128;
  const int K = 2048;

  const int tid  = threadIdx.x;
  const int lane = tid & 63;
  const int w    = tid >> 6;
  const int wm = w >> 1, wn = w & 1;
  const int lm = lane & 15, lq = lane >> 4;

  floatx4 acc[4][4];
  #pragma unroll
  for (int i = 0; i < 4; i++)
    #pragma unroll
    for (int j = 0; j < 4; j++) { floatx4 z = {0.f,0.f,0.f,0.f}; acc[i][j] = z; }

  const int ar = tid >> 2;
  const int ac = (tid & 3) * 8;
  const u16* Ap0 = A  + (size_t)(m0 + ar) * K + ac;
  const u16* Ap1 = A  + (size_t)(m0 + 64 + ar) * K + ac;
  const u16* Bp0 = Bt + (size_t)(n0 + ar) * K + ac;
  const u16* Bp1 = Bt + (size_t)(n0 + 64 + ar) * K + ac;
  u16* sAd = sA + tid * 8;
  u16* sBd = sB + tid * 8;

  for (int k0 = 0; k0 < K; k0 += 32) {
    gld_lds16(Ap0 + k0, sAd);
    gld_lds16(Ap1 + k0, sAd + 2048);
    gld_lds16(Bp0 + k0, sBd);
    gld_lds16(Bp1 + k0, sBd + 2048);
    __syncthreads();

    bf16x8 af[4], bfr[4];
    #pragma unroll
    for (int mi = 0; mi < 4; mi++)
      af[mi] = *(const bf16x8*)(sA + (wm*64 + mi*16 + lm)*32 + lq*8);
    #pragma unroll
    for (int ni = 0; ni < 4; ni++)
      bfr[ni] = *(const bf16x8*)(sB + (wn*64 + ni*16 + lm)*32 + lq*8);

    #pragma unroll
    for (int mi = 0; mi < 4; mi++)
      #pragma unroll
      for (int ni = 0; ni < 4; ni++)
        acc[mi][ni] = __builtin_amdgcn_mfma_f32_16x16x32_bf16(
            af[mi], bfr[ni], acc[mi][ni], 0, 0, 0);
    __syncthreads();
  }

  #pragma unroll
  for (int mi = 0; mi < 4; mi++)
    #pragma unroll
    for (int ni = 0; ni < 4; ni++)
      #pragma unroll
      for (int r = 0; r < 4; r++) {
        int row = m0 + wm*64 + mi*16 + lq*4 + r;
        int col = n0 + wn*64 + ni*16 + lm;
        C[(size_t)row * QKV_W + col] = f2bf(acc[mi][ni][r]);
      }
}

// ---------------------------------------------------------------------------
// GEMM2: out[4096,2048](f32) = attn[4096,2048](bf16) @ wob[2048,2048]^T(bf16)
// ---------------------------------------------------------------------------
__global__ __launch_bounds__(256) void gemm_out_kernel(
    const u16* __restrict__ A, const u16* __restrict__ Bt,
    float* __restrict__ C)
{
  __shared__ __align__(16) u16 sA[128 * 32];
  __shared__ __align__(16) u16 sB[128 * 32];

  const int n0 = blockIdx.x * 128;
  const int m0 = blockIdx.y * 128;
  const int K = 2048;

  const int tid  = threadIdx.x;
  const int lane = tid & 63;
  const int w    = tid >> 6;
  const int wm = w >> 1, wn = w & 1;
  const int lm = lane & 15, lq = lane >> 4;

  floatx4 acc[4][4];
  #pragma unroll
  for (int i = 0; i < 4; i++)
    #pragma unroll
    for (int j = 0; j < 4; j++) { floatx4 z = {0.f,0.f,0.f,0.f}; acc[i][j] = z; }

  const int ar = tid >> 2;
  const int ac = (tid & 3) * 8;
  const u16* Ap0 = A  + (size_t)(m0 + ar) * K + ac;
  const u16* Ap1 = A  + (size_t)(m0 + 64 + ar) * K + ac;
  const u16* Bp0 = Bt + (size_t)(n0 + ar) * K + ac;
  const u16* Bp1 = Bt + (size_t)(n0 + 64 + ar) * K + ac;
  u16* sAd = sA + tid * 8;
  u16* sBd = sB + tid * 8;

  for (int k0 = 0; k0 < K; k0 += 32) {
    gld_lds16(Ap0 + k0, sAd);
    gld_lds16(Ap1 + k0, sAd + 2048);
    gld_lds16(Bp0 + k0, sBd);
    gld_lds16(Bp1 + k0, sBd + 2048);
    __syncthreads();

    bf16x8 af[4], bfr[4];
    #pragma unroll
    for (int mi = 0; mi < 4; mi++)
      af[mi] = *(const bf16x8*)(sA + (wm*64 + mi*16 + lm)*32 + lq*8);
    #pragma unroll
    for (int ni = 0; ni < 4; ni++)
      bfr[ni] = *(const bf16x8*)(sB + (wn*64 + ni*16 + lm)*32 + lq*8);

    #pragma unroll
    for (int mi = 0; mi < 4; mi++)
      #pragma unroll
      for (int ni = 0; ni < 4; ni++)
        acc[mi][ni] = __builtin_amdgcn_mfma_f32_16x16x32_bf16(
            af[mi], bfr[ni], acc[mi][ni], 0, 0, 0);
    __syncthreads();
  }

  #pragma unroll
  for (int mi = 0; mi < 4; mi++)
    #pragma unroll
    for (int ni = 0; ni < 4; ni++)
      #pragma unroll
      for (int r = 0; r < 4; r++) {
        int row = m0 + wm*64 + mi*16 + lq*4 + r;
        int col = n0 + wn*64 + ni*16 + lm;
        C[(size_t)row * DM + col] = acc[mi][ni][r];
      }
}

// ---------------------------------------------------------------------------
// RoPE: reads qkv bf16, writes q (B,H,T,64) bf16 (scaled by 1/8) and
// k (B,KV,T,64) bf16.
// ---------------------------------------------------------------------------
__global__ __launch_bounds__(256) void rope_kernel(
    const u16* __restrict__ qkv, const float* __restrict__ cosf,
    const float* __restrict__ sinf, u16* __restrict__ qb, u16* __restrict__ kb)
{
  const int bt = blockIdx.x;
  const int b = bt / T_SEQ, t = bt % T_SEQ;
  const int tid = threadIdx.x;
  const u16* row = qkv + (size_t)bt * QKV_W;

  #pragma unroll
  for (int i = 0; i < 4; i++) {
    int idx = i * 256 + tid;          // 0..1023
    int h = idx >> 5, dp = idx & 31;
    float x1 = bf2f(row[h * 64 + dp]);
    float x2 = bf2f(row[h * 64 + dp + 32]);
    float c = cosf[t * 64 + dp];
    float s = sinf[t * 64 + dp];
    float o1 = (x1 * c - x2 * s) * 0.125f;
    float o2 = (x2 * c + x1 * s) * 0.125f;
    size_t base = ((size_t)(b * NH + h) * T_SEQ + t) * HD + dp;
    qb[base]      = f2bf(o1);
    qb[base + 32] = f2bf(o2);
  }
  {
    int idx = tid;                    // 0..255
    int kvh = idx >> 5, dp = idx & 31;
    float x1 = bf2f(row[2048 + kvh * 64 + dp]);
    float x2 = bf2f(row[2048 + kvh * 64 + dp + 32]);
    float c = cosf[t * 64 + dp];
    float s = sinf[t * 64 + dp];
    size_t base = ((size_t)(b * NKV + kvh) * T_SEQ + t) * HD + dp;
    kb[base]      = f2bf(x1 * c - x2 * s);
    kb[base + 32] = f2bf(x2 * c + x1 * s);
  }
}

// ---------------------------------------------------------------------------
// V transpose: qkv bf16 cols [2560,3072) -> vbt (B,KV,64,T) bf16
// ---------------------------------------------------------------------------
__global__ __launch_bounds__(256) void vtrans_kernel(
    const u16* __restrict__ qkv, u16* __restrict__ vbt)
{
  __shared__ u16 tile[64][66];
  const int t0  = blockIdx.x * 64;
  const int kvh = blockIdx.y;
  const int b   = blockIdx.z;
  const int tid = threadIdx.x;

  #pragma unroll
  for (int i = 0; i < 16; i++) {
    int idx = i * 256 + tid;
    int r = idx >> 6, c = idx & 63;
    tile[r][c] = qkv[(size_t)(b * T_SEQ + t0 + r) * QKV_W + 2560 + kvh * 64 + c];
  }
  __syncthreads();
  #pragma unroll
  for (int i = 0; i < 16; i++) {
    int idx = i * 256 + tid;
    int d = idx >> 6, c = idx & 63;
    vbt[((size_t)(b * NKV + kvh) * HD + d) * T_SEQ + t0 + c] = tile[c][d];
  }
}

// ---------------------------------------------------------------------------
// Flash attention v2: block = (q-tile 64, h, b); 4 waves x 16 q-rows.
// K/V tiles staged to LDS via global_load_lds (XOR chunk swizzle so
// ds_read_b128 fragment reads are conflict-free).
// QK^T computed TRANSPOSED (S^T = K * Q^T): lane holds q = lane&15,
// k = quad*4+reg -> row stats need only 2 shuffles + in-register reduce,
// and P packs 4 consecutive k per lane (ds_write_b64).
// ---------------------------------------------------------------------------
__global__ __launch_bounds__(256) void attn_kernel(
    const u16* __restrict__ qb, const u16* __restrict__ kb,
    const u16* __restrict__ vbt, u16* __restrict__ attn)
{
  __shared__ __align__(16) u16 sK[64 * 64];     // 8 KB, chunk-swizzled
  __shared__ __align__(16) u16 sV[64 * 64];     // 8 KB, chunk-swizzled
  __shared__ __align__(16) u16 sP[4][16][72];   // P in A-layout, padded
  __shared__ float sAl[4][16];                  // alpha / l transpose slot

  const int tid  = threadIdx.x;
  const int lane = tid & 63;
  const int w    = tid >> 6;
  const int qt = (T_SEQ / 64 - 1) - blockIdx.x;   // long blocks first
  const int h  = blockIdx.y;
  const int b  = blockIdx.z;
  const int kv = h >> 2;
  const int lm = lane & 15, lq = lane >> 4;
  const int sw = lm & 7;                          // XOR swizzle key

  // Q fragment (B-operand: n=q=lm, k=d=lq*8+j), once per block
  const u16* qrow = qb + ((size_t)(b * NH + h) * T_SEQ + (qt * 64 + w * 16 + lm)) * HD + lq * 8;
  bf16x8 qf0 = *(const bf16x8*)(qrow);
  bf16x8 qf1 = *(const bf16x8*)(qrow + 32);

  floatx4 o_acc[4];
  #pragma unroll
  for (int i = 0; i < 4; i++) { floatx4 z = {0.f,0.f,0.f,0.f}; o_acc[i] = z; }
  float m_run = -1e30f;
  float l_run = 0.f;

  const u16* kbase = kb  + (size_t)(b * NKV + kv) * T_SEQ * HD;
  const u16* vbase = vbt + (size_t)(b * NKV + kv) * HD * T_SEQ;

  for (int kt = 0; kt <= qt; kt++) {
    __syncthreads();   // prior iteration's sK/sV reads complete
    // ---- stage K tile (rows t, cols d) and V tile (rows d, cols t) ----
    #pragma unroll
    for (int i = 0; i < 2; i++) {
      int p   = i * 256 + tid;
      int row = p >> 3;
      int ck  = (p & 7) ^ (row & 7);
      gld_lds16(kbase + (size_t)(kt * 64 + row) * HD + ck * 8,
                (char*)sK + p * 16);
      gld_lds16(vbase + (size_t)row * T_SEQ + kt * 64 + ck * 8,
                (char*)sV + p * 16);
    }
    __syncthreads();   // staging visible (vmcnt drained by barrier)

    // ---- S^T = K * Q^T : D[m=k][n=q], lane: q=lm, k=nt*16+lq*4+r ----
    floatx4 s_acc[4];
    #pragma unroll
    for (int nt = 0; nt < 4; nt++) {
      floatx4 z = {0.f,0.f,0.f,0.f};
      bf16x8 kf0 = *(const bf16x8*)(sK + (((nt*16 + lm) * 8 + (lq ^ sw)) << 3));
      bf16x8 kf1 = *(const bf16x8*)(sK + (((nt*16 + lm) * 8 + ((4 + lq) ^ sw)) << 3));
      z = __builtin_amdgcn_mfma_f32_16x16x32_bf16(kf0, qf0, z, 0, 0, 0);
      z = __builtin_amdgcn_mfma_f32_16x16x32_bf16(kf1, qf1, z, 0, 0, 0);
      s_acc[nt] = z;
    }

    if (kt == qt) {   // diagonal tile: causal mask  (k > q)
      #pragma unroll
      for (int nt = 0; nt < 4; nt++)
        #pragma unroll
        for (int r = 0; r < 4; r++)
          if (nt * 16 + lq * 4 + r > w * 16 + lm) s_acc[nt][r] = -1e30f;
    }

    // ---- online softmax: stats per q=lm; in-lane over 16 k + 2 shuffles ----
    float mloc = s_acc[0][0];
    #pragma unroll
    for (int nt = 0; nt < 4; nt++)
      #pragma unroll
      for (int r = 0; r < 4; r++) mloc = fmaxf(mloc, s_acc[nt][r]);
    mloc = fmaxf(mloc, __shfl_xor(mloc, 16));
    mloc = fmaxf(mloc, __shfl_xor(mloc, 32));
    float mnew = fmaxf(m_run, mloc);
    float al = __expf(m_run - mnew);

    float rs = 0.f;
    ushort4 pk[4];
    #pragma unroll
    for (int nt = 0; nt < 4; nt++) {
      float p0 = __expf(s_acc[nt][0] - mnew);
      float p1 = __expf(s_acc[nt][1] - mnew);
      float p2 = __expf(s_acc[nt][2] - mnew);
      float p3 = __expf(s_acc[nt][3] - mnew);
      rs += (p0 + p1) + (p2 + p3);
      pk[nt].x = f2bf(p0); pk[nt].y = f2bf(p1);
      pk[nt].z = f2bf(p2); pk[nt].w = f2bf(p3);
    }
    rs += __shfl_xor(rs, 16);
    rs += __shfl_xor(rs, 32);
    l_run = l_run * al + rs;
    m_run = mnew;

    // ---- P -> LDS (A-layout: sP[w][q=lm][k]) ----
    #pragma unroll
    for (int nt = 0; nt < 4; nt++)
      *(ushort4*)&sP[w][lm][nt * 16 + lq * 4] = pk[nt];

    // ---- alpha transpose: need alpha(q = lq*4+r) for o_acc scaling ----
    sAl[w][lm] = al;
    floatx4 alv = *(const floatx4*)&sAl[w][lq * 4];
    #pragma unroll
    for (int nt2 = 0; nt2 < 4; nt2++)
      #pragma unroll
      for (int r = 0; r < 4; r++)
        o_acc[nt2][r] *= alv[r];

    // ---- O += P * V ----
    #pragma unroll
    for (int st = 0; st < 2; st++) {
      bf16x8 pf = *(const bf16x8*)(&sP[w][lm][st * 32 + lq * 8]);
      #pragma unroll
      for (int nt2 = 0; nt2 < 4; nt2++) {
        bf16x8 vf = *(const bf16x8*)(sV + (((nt2*16 + lm) * 8 + ((st*4 + lq) ^ sw)) << 3));
        o_acc[nt2] = __builtin_amdgcn_mfma_f32_16x16x32_bf16(pf, vf, o_acc[nt2], 0, 0, 0);
      }
    }
  }

  // ---- epilogue: transpose l, normalize, store ----
  sAl[w][lm] = l_run;
  floatx4 lv = *(const floatx4*)&sAl[w][lq * 4];
  #pragma unroll
  for (int nt2 = 0; nt2 < 4; nt2++)
    #pragma unroll
    for (int r = 0; r < 4; r++) {
      float v = o_acc[nt2][r] / lv[r];
      size_t row = (size_t)b * T_SEQ + qt * 64 + w * 16 + lq * 4 + r;
      attn[row * DM + h * HD + nt2 * 16 + lm] = f2bf(v);
    }
}

// ---------------------------------------------------------------------------
extern "C" void kernel_launch(void* const* d_in, const int* in_sizes, int n_in,
                              void* d_out, int out_size, void* d_ws, size_t ws_size,
                              hipStream_t stream)
{
  const float* x    = (const float*)d_in[0];
  const float* cosf = (const float*)d_in[1];
  const float* sinf = (const float*)d_in[2];
  const float* Wq   = (const float*)d_in[3];
  const float* Wk   = (const float*)d_in[4];
  const float* Wv   = (const float*)d_in[5];
  const float* Wo   = (const float*)d_in[6];
  float* out = (float*)d_out;

  char* ws = (char*)d_ws;
  u16* qkvb  = (u16*)(ws + 0);          // 4096x3072 bf16 = 25,165,824
  u16* attnb = (u16*)(ws + 0);          // reuse after rope/vtrans
  u16* qb    = (u16*)(ws + 25165824);   // 16,777,216
  u16* kb    = (u16*)(ws + 41943040);   //  4,194,304
  u16* vbt   = (u16*)(ws + 46137344);   //  4,194,304
  u16* xb    = (u16*)(ws + 50331648);   // 16,777,216 (dead after gemm_qkv)
  u16* wob   = (u16*)(ws + 50331648);   //  8,388,608 (overwrites xb)
  u16* wqkvb = (u16*)(ws + 67108864);   // 12,582,912

  dim3 blk(256);
  conv_kernel<<<dim3(2048), blk, 0, stream>>>(x,  xb,                 8388608 / 4);
  conv_kernel<<<dim3(1024), blk, 0, stream>>>(Wq, wqkvb,              4194304 / 4);
  conv_kernel<<<dim3(512),  blk, 0, stream>>>(Wk, wqkvb + 2048*2048,  1048576 / 4);
  conv_kernel<<<dim3(512),  blk, 0, stream>>>(Wv, wqkvb + 2560*2048,  1048576 / 4);

  gemm_qkv_kernel<<<dim3(24, 32), blk, 0, stream>>>(xb, wqkvb, qkvb);

  conv_kernel<<<dim3(1024), blk, 0, stream>>>(Wo, wob, 4194304 / 4);

  rope_kernel<<<dim3(B_SZ * T_SEQ), blk, 0, stream>>>(qkvb, cosf, sinf, qb, kb);
  vtrans_kernel<<<dim3(T_SEQ / 64, NKV, B_SZ), blk, 0, stream>>>(qkvb, vbt);
  attn_kernel<<<dim3(T_SEQ / 64, NH, B_SZ), blk, 0, stream>>>(qb, kb, vbt, attnb);
  gemm_out_kernel<<<dim3(16, 32), blk, 0, stream>>>(attnb, wob, out);
}

// Round 4
// 341.279 us; speedup vs baseline: 2.0281x; 1.1349x over previous
//
#include <hip/hip_runtime.h>
#include <stdint.h>

// Problem constants
#define B_SZ 2
#define T_SEQ 2048
#define DM 2048
#define NH 32
#define NKV 8
#define HD 64
#define QKV_W 3072

typedef unsigned short u16;
typedef __bf16 bf16x8 __attribute__((ext_vector_type(8)));
typedef float floatx4 __attribute__((ext_vector_type(4)));

__device__ __forceinline__ float bf2f(u16 u) {
  union { unsigned u; float f; } v; v.u = ((unsigned)u) << 16; return v.f;
}
__device__ __forceinline__ u16 f2bf(float f) {
  union { float f; unsigned u; } v; v.f = f;
  unsigned r = v.u + 0x7fff + ((v.u >> 16) & 1);   // RNE
  return (u16)(r >> 16);
}
// pack 2 f32 -> 2 bf16 (truncation) in one v_perm
__device__ __forceinline__ unsigned pk2bf(float hi, float lo) {
  return __builtin_amdgcn_perm(__float_as_uint(hi), __float_as_uint(lo), 0x07060302u);
}
__device__ __forceinline__ float fexp2(float x) {
#if __has_builtin(__builtin_amdgcn_exp2f)
  return __builtin_amdgcn_exp2f(x);
#else
  return exp2f(x);
#endif
}

__device__ __forceinline__ void gld_lds16(const void* g, void* l) {
  __builtin_amdgcn_global_load_lds(
      (const __attribute__((address_space(1))) unsigned int*)g,
      (__attribute__((address_space(3))) unsigned int*)l, 16, 0, 0);
}

// ---------------------------------------------------------------------------
// f32 -> bf16 conversion (RNE), vectorized float4 -> ushort4, grid-stride.
// ---------------------------------------------------------------------------
__global__ __launch_bounds__(256) void conv_kernel(
    const float* __restrict__ src, u16* __restrict__ dst, int n4)
{
  int i = blockIdx.x * 256 + threadIdx.x;
  int stride = gridDim.x * 256;
  for (; i < n4; i += stride) {
    float4 v = ((const float4*)src)[i];
    ushort4 o;
    o.x = f2bf(v.x); o.y = f2bf(v.y); o.z = f2bf(v.z); o.w = f2bf(v.w);
    ((ushort4*)dst)[i] = o;
  }
}

// ---------------------------------------------------------------------------
// GEMM1: qkv[4096,3072](bf16) = xb[4096,2048](bf16) @ wqkvb[3072,2048]^T
// ---------------------------------------------------------------------------
__global__ __launch_bounds__(256) void gemm_qkv_kernel(
    const u16* __restrict__ A, const u16* __restrict__ Bt,
    u16* __restrict__ C)
{
  __shared__ __align__(16) u16 sA[128 * 32];
  __shared__ __align__(16) u16 sB[128 * 32];

  const int n0 = blockIdx.x * 128;
  const int m0 = blockIdx.y * 128;
  const int K = 2048;

  const int tid  = threadIdx.x;
  const int lane = tid & 63;
  const int w    = tid >> 6;
  const int wm = w >> 1, wn = w & 1;
  const int lm = lane & 15, lq = lane >> 4;

  floatx4 acc[4][4];
  #pragma unroll
  for (int i = 0; i < 4; i++)
    #pragma unroll
    for (int j = 0; j < 4; j++) { floatx4 z = {0.f,0.f,0.f,0.f}; acc[i][j] = z; }

  const int ar = tid >> 2;
  const int ac = (tid & 3) * 8;
  const u16* Ap0 = A  + (size_t)(m0 + ar) * K + ac;
  const u16* Ap1 = A  + (size_t)(m0 + 64 + ar) * K + ac;
  const u16* Bp0 = Bt + (size_t)(n0 + ar) * K + ac;
  const u16* Bp1 = Bt + (size_t)(n0 + 64 + ar) * K + ac;
  u16* sAd = sA + tid * 8;
  u16* sBd = sB + tid * 8;

  for (int k0 = 0; k0 < K; k0 += 32) {
    gld_lds16(Ap0 + k0, sAd);
    gld_lds16(Ap1 + k0, sAd + 2048);
    gld_lds16(Bp0 + k0, sBd);
    gld_lds16(Bp1 + k0, sBd + 2048);
    __syncthreads();

    bf16x8 af[4], bfr[4];
    #pragma unroll
    for (int mi = 0; mi < 4; mi++)
      af[mi] = *(const bf16x8*)(sA + (wm*64 + mi*16 + lm)*32 + lq*8);
    #pragma unroll
    for (int ni = 0; ni < 4; ni++)
      bfr[ni] = *(const bf16x8*)(sB + (wn*64 + ni*16 + lm)*32 + lq*8);

    #pragma unroll
    for (int mi = 0; mi < 4; mi++)
      #pragma unroll
      for (int ni = 0; ni < 4; ni++)
        acc[mi][ni] = __builtin_amdgcn_mfma_f32_16x16x32_bf16(
            af[mi], bfr[ni], acc[mi][ni], 0, 0, 0);
    __syncthreads();
  }

  #pragma unroll
  for (int mi = 0; mi < 4; mi++)
    #pragma unroll
    for (int ni = 0; ni < 4; ni++)
      #pragma unroll
      for (int r = 0; r < 4; r++) {
        int row = m0 + wm*64 + mi*16 + lq*4 + r;
        int col = n0 + wn*64 + ni*16 + lm;
        C[(size_t)row * QKV_W + col] = f2bf(acc[mi][ni][r]);
      }
}

// ---------------------------------------------------------------------------
// GEMM2: out[4096,2048](f32) = attn[4096,2048](bf16) @ wob[2048,2048]^T(bf16)
// ---------------------------------------------------------------------------
__global__ __launch_bounds__(256) void gemm_out_kernel(
    const u16* __restrict__ A, const u16* __restrict__ Bt,
    float* __restrict__ C)
{
  __shared__ __align__(16) u16 sA[128 * 32];
  __shared__ __align__(16) u16 sB[128 * 32];

  const int n0 = blockIdx.x * 128;
  const int m0 = blockIdx.y * 128;
  const int K = 2048;

  const int tid  = threadIdx.x;
  const int lane = tid & 63;
  const int w    = tid >> 6;
  const int wm = w >> 1, wn = w & 1;
  const int lm = lane & 15, lq = lane >> 4;

  floatx4 acc[4][4];
  #pragma unroll
  for (int i = 0; i < 4; i++)
    #pragma unroll
    for (int j = 0; j < 4; j++) { floatx4 z = {0.f,0.f,0.f,0.f}; acc[i][j] = z; }

  const int ar = tid >> 2;
  const int ac = (tid & 3) * 8;
  const u16* Ap0 = A  + (size_t)(m0 + ar) * K + ac;
  const u16* Ap1 = A  + (size_t)(m0 + 64 + ar) * K + ac;
  const u16* Bp0 = Bt + (size_t)(n0 + ar) * K + ac;
  const u16* Bp1 = Bt + (size_t)(n0 + 64 + ar) * K + ac;
  u16* sAd = sA + tid * 8;
  u16* sBd = sB + tid * 8;

  for (int k0 = 0; k0 < K; k0 += 32) {
    gld_lds16(Ap0 + k0, sAd);
    gld_lds16(Ap1 + k0, sAd + 2048);
    gld_lds16(Bp0 + k0, sBd);
    gld_lds16(Bp1 + k0, sBd + 2048);
    __syncthreads();

    bf16x8 af[4], bfr[4];
    #pragma unroll
    for (int mi = 0; mi < 4; mi++)
      af[mi] = *(const bf16x8*)(sA + (wm*64 + mi*16 + lm)*32 + lq*8);
    #pragma unroll
    for (int ni = 0; ni < 4; ni++)
      bfr[ni] = *(const bf16x8*)(sB + (wn*64 + ni*16 + lm)*32 + lq*8);

    #pragma unroll
    for (int mi = 0; mi < 4; mi++)
      #pragma unroll
      for (int ni = 0; ni < 4; ni++)
        acc[mi][ni] = __builtin_amdgcn_mfma_f32_16x16x32_bf16(
            af[mi], bfr[ni], acc[mi][ni], 0, 0, 0);
    __syncthreads();
  }

  #pragma unroll
  for (int mi = 0; mi < 4; mi++)
    #pragma unroll
    for (int ni = 0; ni < 4; ni++)
      #pragma unroll
      for (int r = 0; r < 4; r++) {
        int row = m0 + wm*64 + mi*16 + lq*4 + r;
        int col = n0 + wn*64 + ni*16 + lm;
        C[(size_t)row * DM + col] = acc[mi][ni][r];
      }
}

// ---------------------------------------------------------------------------
// RoPE: q scaled by (1/sqrt(64)) * log2(e) so attention can use raw v_exp2.
// q (B,H,T,64) bf16, k (B,KV,T,64) bf16.
// ---------------------------------------------------------------------------
#define QSCALE 0.180336880f   // 0.125 * 1.44269504
__global__ __launch_bounds__(256) void rope_kernel(
    const u16* __restrict__ qkv, const float* __restrict__ cosf,
    const float* __restrict__ sinf, u16* __restrict__ qb, u16* __restrict__ kb)
{
  const int bt = blockIdx.x;
  const int b = bt / T_SEQ, t = bt % T_SEQ;
  const int tid = threadIdx.x;
  const u16* row = qkv + (size_t)bt * QKV_W;

  #pragma unroll
  for (int i = 0; i < 4; i++) {
    int idx = i * 256 + tid;          // 0..1023
    int h = idx >> 5, dp = idx & 31;
    float x1 = bf2f(row[h * 64 + dp]);
    float x2 = bf2f(row[h * 64 + dp + 32]);
    float c = cosf[t * 64 + dp];
    float s = sinf[t * 64 + dp];
    float o1 = (x1 * c - x2 * s) * QSCALE;
    float o2 = (x2 * c + x1 * s) * QSCALE;
    size_t base = ((size_t)(b * NH + h) * T_SEQ + t) * HD + dp;
    qb[base]      = f2bf(o1);
    qb[base + 32] = f2bf(o2);
  }
  {
    int idx = tid;                    // 0..255
    int kvh = idx >> 5, dp = idx & 31;
    float x1 = bf2f(row[2048 + kvh * 64 + dp]);
    float x2 = bf2f(row[2048 + kvh * 64 + dp + 32]);
    float c = cosf[t * 64 + dp];
    float s = sinf[t * 64 + dp];
    size_t base = ((size_t)(b * NKV + kvh) * T_SEQ + t) * HD + dp;
    kb[base]      = f2bf(x1 * c - x2 * s);
    kb[base + 32] = f2bf(x2 * c + x1 * s);
  }
}

// ---------------------------------------------------------------------------
// V transpose: qkv bf16 cols [2560,3072) -> vbt (B,KV,64,T) bf16
// ---------------------------------------------------------------------------
__global__ __launch_bounds__(256) void vtrans_kernel(
    const u16* __restrict__ qkv, u16* __restrict__ vbt)
{
  __shared__ u16 tile[64][66];
  const int t0  = blockIdx.x * 64;
  const int kvh = blockIdx.y;
  const int b   = blockIdx.z;
  const int tid = threadIdx.x;

  #pragma unroll
  for (int i = 0; i < 16; i++) {
    int idx = i * 256 + tid;
    int r = idx >> 6, c = idx & 63;
    tile[r][c] = qkv[(size_t)(b * T_SEQ + t0 + r) * QKV_W + 2560 + kvh * 64 + c];
  }
  __syncthreads();
  #pragma unroll
  for (int i = 0; i < 16; i++) {
    int idx = i * 256 + tid;
    int d = idx >> 6, c = idx & 63;
    vbt[((size_t)(b * NKV + kvh) * HD + d) * T_SEQ + t0 + c] = tile[c][d];
  }
}

// ---------------------------------------------------------------------------
// Flash attention v3 (GQA-fused): block = (q-tile 64, KV-GROUP, b);
// wave w handles q-head kv*4+w. K/V staged ONCE per block for all 4 heads.
// Per wave per k-tile: 64q x 64k scores (S^T = K*Q^T, 32 MFMA) + online
// softmax + PV (32 MFMA). exp via raw v_exp_f32 (log2e folded into q scale),
// bf16 P-pack via v_perm (truncation).
// Dispatch swizzle pairs long (qt=31-j) and short (qt=j) blocks per CU.
// ---------------------------------------------------------------------------
__global__ __launch_bounds__(256, 2) void attn_kernel(
    const u16* __restrict__ qb, const u16* __restrict__ kb,
    const u16* __restrict__ vbt, u16* __restrict__ attn)
{
  __shared__ __align__(16) u16 sK[64 * 64];     // 8 KB, chunk-swizzled
  __shared__ __align__(16) u16 sV[64 * 64];     // 8 KB, chunk-swizzled
  __shared__ __align__(16) u16 sP[4][16][72];   // per-wave P, A-layout
  __shared__ float sAl[4][16];                  // alpha / l transpose slot

  const int tid  = threadIdx.x;
  const int lane = tid & 63;
  const int w    = tid >> 6;

  // makespan-balancing swizzle: linear id l; halves pair qt j with 31-j
  const int l    = blockIdx.x;
  const int half = l >> 8;
  const int r_   = l & 255;
  const int qt   = half ? (31 - (r_ & 31)) : (r_ & 31);
  const int kv   = (r_ >> 5) & 7;
  const int b    = half;
  const int h    = kv * 4 + w;

  const int lm = lane & 15, lq = lane >> 4;
  const int sw = lm & 7;                          // XOR swizzle key

  // Q fragments (B-operand): qf[nq][c] covers q = qt*64+nq*16+lm, d = c*32+lq*8
  bf16x8 qf[4][2];
  {
    const u16* qhead = qb + ((size_t)(b * NH + h) * T_SEQ + qt * 64) * HD;
    #pragma unroll
    for (int nq = 0; nq < 4; nq++) {
      const u16* qrow = qhead + (size_t)(nq * 16 + lm) * HD + lq * 8;
      qf[nq][0] = *(const bf16x8*)(qrow);
      qf[nq][1] = *(const bf16x8*)(qrow + 32);
    }
  }

  floatx4 o_acc[4][4];
  #pragma unroll
  for (int i = 0; i < 4; i++)
    #pragma unroll
    for (int j = 0; j < 4; j++) { floatx4 z = {0.f,0.f,0.f,0.f}; o_acc[i][j] = z; }
  float m_run[4] = {-1e30f, -1e30f, -1e30f, -1e30f};
  float l_run[4] = {0.f, 0.f, 0.f, 0.f};

  const u16* kbase = kb  + (size_t)(b * NKV + kv) * T_SEQ * HD;
  const u16* vbase = vbt + (size_t)(b * NKV + kv) * HD * T_SEQ;

  // precomputed staging lane addresses
  const int p0row = tid >> 3,        p1row = (256 + tid) >> 3;
  const int p0ck  = (tid & 7) ^ (p0row & 7), p1ck = ((256 + tid) & 7) ^ (p1row & 7);
  const u16* kp0 = kbase + (size_t)p0row * HD + p0ck * 8;
  const u16* kp1 = kbase + (size_t)p1row * HD + p1ck * 8;
  const u16* vp0 = vbase + (size_t)p0row * T_SEQ + p0ck * 8;
  const u16* vp1 = vbase + (size_t)p1row * T_SEQ + p1ck * 8;
  char* sKd0 = (char*)sK + tid * 16;        char* sKd1 = (char*)sK + (256 + tid) * 16;
  char* sVd0 = (char*)sV + tid * 16;        char* sVd1 = (char*)sV + (256 + tid) * 16;

  for (int kt = 0; kt <= qt; kt++) {
    __syncthreads();   // prior iteration's sK/sV reads complete
    gld_lds16(kp0 + (size_t)kt * 64 * HD, sKd0);
    gld_lds16(kp1 + (size_t)kt * 64 * HD, sKd1);
    gld_lds16(vp0 + kt * 64, sVd0);
    gld_lds16(vp1 + kt * 64, sVd1);
    __syncthreads();   // staging visible

    // K fragments (A-operand) and V fragments (B-operand), shared across nq
    bf16x8 kf[4][2], vf[4][2];
    #pragma unroll
    for (int nt = 0; nt < 4; nt++) {
      kf[nt][0] = *(const bf16x8*)(sK + (((nt*16 + lm) * 8 + (lq ^ sw)) << 3));
      kf[nt][1] = *(const bf16x8*)(sK + (((nt*16 + lm) * 8 + ((4 + lq) ^ sw)) << 3));
      vf[nt][0] = *(const bf16x8*)(sV + (((nt*16 + lm) * 8 + (lq ^ sw)) << 3));
      vf[nt][1] = *(const bf16x8*)(sV + (((nt*16 + lm) * 8 + ((4 + lq) ^ sw)) << 3));
    }

    #pragma unroll
    for (int nq = 0; nq < 4; nq++) {
      // ---- S^T tile: D[m=k][n=q], lane: q=lm (+16nq), k=nt*16+lq*4+r ----
      floatx4 s_acc[4];
      #pragma unroll
      for (int nt = 0; nt < 4; nt++) {
        floatx4 z = {0.f,0.f,0.f,0.f};
        z = __builtin_amdgcn_mfma_f32_16x16x32_bf16(kf[nt][0], qf[nq][0], z, 0, 0, 0);
        z = __builtin_amdgcn_mfma_f32_16x16x32_bf16(kf[nt][1], qf[nq][1], z, 0, 0, 0);
        s_acc[nt] = z;
      }

      if (kt == qt) {   // diagonal tile: causal mask (k > q)
        #pragma unroll
        for (int nt = 0; nt < 4; nt++)
          #pragma unroll
          for (int r = 0; r < 4; r++)
            if (nt * 16 + lq * 4 + r > nq * 16 + lm) s_acc[nt][r] = -1e30f;
      }

      // ---- online softmax (scores already in log2 domain) ----
      float mloc = s_acc[0][0];
      #pragma unroll
      for (int nt = 0; nt < 4; nt++)
        #pragma unroll
        for (int r = 0; r < 4; r++) mloc = fmaxf(mloc, s_acc[nt][r]);
      mloc = fmaxf(mloc, __shfl_xor(mloc, 16));
      mloc = fmaxf(mloc, __shfl_xor(mloc, 32));
      float mnew = fmaxf(m_run[nq], mloc);
      float al = fexp2(m_run[nq] - mnew);

      float rs = 0.f;
      uint2 pk[4];
      #pragma unroll
      for (int nt = 0; nt < 4; nt++) {
        float p0 = fexp2(s_acc[nt][0] - mnew);
        float p1 = fexp2(s_acc[nt][1] - mnew);
        float p2 = fexp2(s_acc[nt][2] - mnew);
        float p3 = fexp2(s_acc[nt][3] - mnew);
        rs += (p0 + p1) + (p2 + p3);
        pk[nt].x = pk2bf(p1, p0);
        pk[nt].y = pk2bf(p3, p2);
      }
      rs += __shfl_xor(rs, 16);
      rs += __shfl_xor(rs, 32);
      l_run[nq] = l_run[nq] * al + rs;
      m_run[nq] = mnew;

      // ---- P -> LDS (A-layout: sP[w][q=lm][k]) ----
      #pragma unroll
      for (int nt = 0; nt < 4; nt++)
        *(uint2*)&sP[w][lm][nt * 16 + lq * 4] = pk[nt];

      // ---- alpha transpose + rescale O ----
      if (lq == 0) sAl[w][lm] = al;
      floatx4 alv = *(const floatx4*)&sAl[w][lq * 4];
      #pragma unroll
      for (int nd = 0; nd < 4; nd++)
        #pragma unroll
        for (int r = 0; r < 4; r++)
          o_acc[nq][nd][r] *= alv[r];

      // ---- O[nq] += P * V ----
      #pragma unroll
      for (int st = 0; st < 2; st++) {
        bf16x8 pf = *(const bf16x8*)(&sP[w][lm][st * 32 + lq * 8]);
        #pragma unroll
        for (int nd = 0; nd < 4; nd++)
          o_acc[nq][nd] = __builtin_amdgcn_mfma_f32_16x16x32_bf16(
              pf, vf[nd][st], o_acc[nq][nd], 0, 0, 0);
      }
    }
  }

  // ---- epilogue: per nq transpose l, normalize, store ----
  #pragma unroll
  for (int nq = 0; nq < 4; nq++) {
    __builtin_amdgcn_s_waitcnt(0);  // ensure prior sAl use complete (same wave)
    if (lq == 0) sAl[w][lm] = l_run[nq];
    floatx4 lv = *(const floatx4*)&sAl[w][lq * 4];
    #pragma unroll
    for (int nd = 0; nd < 4; nd++)
      #pragma unroll
      for (int r = 0; r < 4; r++) {
        float v = o_acc[nq][nd][r] / lv[r];
        size_t row = (size_t)b * T_SEQ + qt * 64 + nq * 16 + lq * 4 + r;
        attn[row * DM + h * HD + nd * 16 + lm] = f2bf(v);
      }
  }
}

// ---------------------------------------------------------------------------
extern "C" void kernel_launch(void* const* d_in, const int* in_sizes, int n_in,
                              void* d_out, int out_size, void* d_ws, size_t ws_size,
                              hipStream_t stream)
{
  const float* x    = (const float*)d_in[0];
  const float* cosf = (const float*)d_in[1];
  const float* sinf = (const float*)d_in[2];
  const float* Wq   = (const float*)d_in[3];
  const float* Wk   = (const float*)d_in[4];
  const float* Wv   = (const float*)d_in[5];
  const float* Wo   = (const float*)d_in[6];
  float* out = (float*)d_out;

  char* ws = (char*)d_ws;
  u16* qkvb  = (u16*)(ws + 0);          // 4096x3072 bf16 = 25,165,824
  u16* attnb = (u16*)(ws + 0);          // reuse after rope/vtrans
  u16* qb    = (u16*)(ws + 25165824);   // 16,777,216
  u16* kb    = (u16*)(ws + 41943040);   //  4,194,304
  u16* vbt   = (u16*)(ws + 46137344);   //  4,194,304
  u16* xb    = (u16*)(ws + 50331648);   // 16,777,216 (dead after gemm_qkv)
  u16* wob   = (u16*)(ws + 50331648);   //  8,388,608 (overwrites xb)
  u16* wqkvb = (u16*)(ws + 67108864);   // 12,582,912

  dim3 blk(256);
  conv_kernel<<<dim3(2048), blk, 0, stream>>>(x,  xb,                 8388608 / 4);
  conv_kernel<<<dim3(1024), blk, 0, stream>>>(Wq, wqkvb,              4194304 / 4);
  conv_kernel<<<dim3(512),  blk, 0, stream>>>(Wk, wqkvb + 2048*2048,  1048576 / 4);
  conv_kernel<<<dim3(512),  blk, 0, stream>>>(Wv, wqkvb + 2560*2048,  1048576 / 4);

  gemm_qkv_kernel<<<dim3(24, 32), blk, 0, stream>>>(xb, wqkvb, qkvb);

  conv_kernel<<<dim3(1024), blk, 0, stream>>>(Wo, wob, 4194304 / 4);

  rope_kernel<<<dim3(B_SZ * T_SEQ), blk, 0, stream>>>(qkvb, cosf, sinf, qb, kb);
  vtrans_kernel<<<dim3(T_SEQ / 64, NKV, B_SZ), blk, 0, stream>>>(qkvb, vbt);
  attn_kernel<<<dim3(512), blk, 0, stream>>>(qb, kb, vbt, attnb);
  gemm_out_kernel<<<dim3(16, 32), blk, 0, stream>>>(attnb, wob, out);
}